// Round 13
// baseline (393.689 us; speedup 1.0000x reference)
//
#include <hip/hip_runtime.h>

#define R_NODES 100000
#define I_DIM 512
#define K_SEL 512

// ---- workspace layout (bytes) ----
#define OFF_NORM   0                                    // 1 float
#define OFF_GHIST  256                                  // 2048 uint = 8192 B
#define OFF_KEYS   8704                                 // 100000 uint = 400000 B
#define OFF_SELIDX 408832                               // 512 int
#define OFF_SELW   410880                               // 512 float
#define OFF_XT     413696                               // bXt bf16 [j][k] 512*512*2 = 524288
#define OFF_HT     (OFF_XT + 524288)                    // bHt bf16 [j][k] (H^T) 524288
#define OFF_W6     (OFF_HT + 524288)                    // 6 bf16 weights (Wu,Uu,Wr,Ur,Wh,Uh)
#define OFF_U      (OFF_W6 + 6 * 524288)                // U f32 [i][j] 1 MB
#define OFF_RHT    (OFF_U + 1048576)                    // bRHt bf16 [j][i] 524288
// total ~6.2 MB

// k_front grid partition
#define NB_SCORES 12500                                 // 8 rows/block
#define NB_W      1536                                  // 6 matrices * 256 blocks
#define NB_HT     256                                   // 16x16 tiles of 32x32

typedef __attribute__((ext_vector_type(8))) short bf16x8;   // MFMA A/B frag (4 VGPR)
typedef __attribute__((ext_vector_type(4))) float f32x4;    // MFMA C/D frag

__device__ __forceinline__ float sigf(float x) { return 1.0f / (1.0f + __expf(-x)); }
__device__ __forceinline__ unsigned short bfr(float x) {   // f32 -> bf16 RNE
  unsigned int u = __float_as_uint(x);
  u += 0x7FFFu + ((u >> 16) & 1u);
  return (unsigned short)(u >> 16);
}
__device__ __forceinline__ unsigned int key_enc(float score) {
  unsigned int u = __float_as_uint(score);
  return (u & 0x80000000u) ? ~u : (u | 0x80000000u);
}
// LDS XOR swizzle for [64 rows][32 k] bf16 tiles (64 B rows)
#define LDS_SWZ(row, bytecol) ((((row) * 64) + (bytecol)) ^ (((row) & 7) << 4))

// ---- kernel 0: scorer norm + zero global histogram ----
__global__ __launch_bounds__(256) void k_norm(const float* __restrict__ scorer,
                                              float* __restrict__ inv_norm,
                                              unsigned int* __restrict__ ghist) {
  __shared__ float red[256];
  int t = threadIdx.x;
  for (int b = t; b < 2048; b += 256) ghist[b] = 0u;
  float v0 = scorer[t], v1 = scorer[t + 256];
  red[t] = v0 * v0 + v1 * v1;
  __syncthreads();
  for (int s = 128; s > 0; s >>= 1) {
    if (t < s) red[t] += red[t + s];
    __syncthreads();
  }
  if (t == 0) inv_norm[0] = 1.0f / (sqrtf(red[0]) + 1e-12f);
}

// ---- kernel 1 (merged): scores (2 rows/wave) + weight->bf16 cvt + H^T cvt ----
__global__ __launch_bounds__(256) void k_front(
    const float* __restrict__ inputs, const float* __restrict__ scorer,
    const float* __restrict__ mask, const float* __restrict__ inv_norm,
    unsigned int* __restrict__ keys,
    const float* __restrict__ Wu, const float* __restrict__ Uu,
    const float* __restrict__ Wr, const float* __restrict__ Ur,
    const float* __restrict__ Wh, const float* __restrict__ Uh,
    const float* __restrict__ hist,
    unsigned short* __restrict__ bW, unsigned short* __restrict__ bHt) {
  const int bx = blockIdx.x;
  const int t = threadIdx.x;
  if (bx < NB_SCORES) {
    const int wave = t >> 6;
    const int lane = t & 63;
    const int row0 = bx * 8 + wave * 2;
    const float4* sp = (const float4*)scorer;
    float4 s0 = sp[lane], s1 = sp[lane + 64];
    const float4* rp0 = (const float4*)(inputs + (size_t)row0 * I_DIM);
    const float4* rp1 = (const float4*)(inputs + (size_t)(row0 + 1) * I_DIM);
    float4 a0 = rp0[lane], a1 = rp0[lane + 64];
    float4 b0 = rp1[lane], b1 = rp1[lane + 64];
    float d0 = a0.x * s0.x + a0.y * s0.y + a0.z * s0.z + a0.w * s0.w
             + a1.x * s1.x + a1.y * s1.y + a1.z * s1.z + a1.w * s1.w;
    float d1 = b0.x * s0.x + b0.y * s0.y + b0.z * s0.z + b0.w * s0.w
             + b1.x * s1.x + b1.y * s1.y + b1.z * s1.z + b1.w * s1.w;
#pragma unroll
    for (int off = 32; off >= 1; off >>= 1) {
      d0 += __shfl_down(d0, off);
      d1 += __shfl_down(d1, off);
    }
    if (lane == 0) {
      float inv = inv_norm[0];
      keys[row0] = key_enc(d0 * inv + mask[row0]);
      keys[row0 + 1] = key_enc(d1 * inv + mask[row0 + 1]);
    }
  } else if (bx < NB_SCORES + NB_W) {
    const int widx = bx - NB_SCORES;
    const int y = widx >> 8;          // 0..5
    const float* srcs[6] = {Wu, Uu, Wr, Ur, Wh, Uh};
    const float* src = srcs[y];
    unsigned short* dst = bW + (size_t)y * (I_DIM * I_DIM);
    int idx4 = (widx & 255) * 256 + t;  // 256 sub-blocks * 256 thr * 4 = 262144
    float4 v = ((const float4*)src)[idx4];
    ushort4 o;
    o.x = bfr(v.x); o.y = bfr(v.y); o.z = bfr(v.z); o.w = bfr(v.w);
    ((ushort4*)dst)[idx4] = o;
  } else {
    __shared__ float tile[32][33];
    const int bxx = bx - NB_SCORES - NB_W;  // 0..255
    const int ti = bxx >> 4;   // source row tile
    const int tj = bxx & 15;   // source col tile
    const int r = t >> 3;
    const int cq = (t & 7) * 4;
    float4 v = *(const float4*)&hist[(ti * 32 + r) * I_DIM + tj * 32 + cq];
    tile[r][cq + 0] = v.x; tile[r][cq + 1] = v.y;
    tile[r][cq + 2] = v.z; tile[r][cq + 3] = v.w;
    __syncthreads();
    ushort4 o;
    o.x = bfr(tile[cq + 0][r]);
    o.y = bfr(tile[cq + 1][r]);
    o.z = bfr(tile[cq + 2][r]);
    o.w = bfr(tile[cq + 3][r]);
    *(ushort4*)&bHt[(tj * 32 + r) * I_DIM + ti * 32 + cq] = o;
  }
}

// ---- kernel 2: grid-wide histogram of top 11 key bits (UNCHANGED) ----
__global__ __launch_bounds__(256) void k_hist1(const unsigned int* __restrict__ keys,
                                               unsigned int* __restrict__ ghist) {
  __shared__ unsigned int h[2048];
  int t = threadIdx.x;
  for (int b = t; b < 2048; b += 256) h[b] = 0u;
  __syncthreads();
  int per = (R_NODES + gridDim.x - 1) / gridDim.x;
  int start = blockIdx.x * per;
  int end = start + per;
  if (end > R_NODES) end = R_NODES;
  for (int r = start + t; r < end; r += 256) atomicAdd(&h[keys[r] >> 21], 1u);
  __syncthreads();
  for (int b = t; b < 2048; b += 256) {
    unsigned int v = h[b];
    if (v) atomicAdd(&ghist[b], v);
  }
}

// ---- kernel 3: select (UNCHANGED from round-11-verified v2) ----
#define SUFFIX_SCAN()                                                         \
  for (int off = 1; off < 2048; off <<= 1) {                                  \
    unsigned int v0 = (t + off < 2048) ? hist[t + off] : 0u;                  \
    unsigned int v1 = (t + 1024 + off < 2048) ? hist[t + 1024 + off] : 0u;    \
    __syncthreads();                                                          \
    hist[t] += v0;                                                            \
    hist[t + 1024] += v1;                                                     \
    __syncthreads();                                                          \
  }

#define FIND_BIN(needv)                                                       \
  {                                                                           \
    for (int q = 0; q < 2; ++q) {                                             \
      int b = t + q * 1024;                                                   \
      unsigned int s_here = hist[b];                                          \
      unsigned int s_next = (b < 2047) ? hist[b + 1] : 0u;                    \
      if (s_here >= (needv) && s_next < (needv)) {                            \
        sh_bin = (unsigned int)b;                                             \
      }                                                                       \
    }                                                                         \
    __syncthreads();                                                          \
  }

__global__ __launch_bounds__(1024) void k_select(const unsigned int* __restrict__ keys,
                                                 const unsigned int* __restrict__ ghist,
                                                 int* __restrict__ sel_idx,
                                                 float* __restrict__ sel_w) {
  __shared__ unsigned int hist[2048];
  __shared__ unsigned long long cand[2048];
  __shared__ unsigned int sh_bin, sh_cnt;
  const int t = threadIdx.x;

  hist[t] = ghist[t];
  hist[t + 1024] = ghist[t + 1024];
  __syncthreads();
  SUFFIX_SCAN();
  FIND_BIN(K_SEL);
  unsigned int b1 = sh_bin;
  if (t == 0) sh_cnt = 0u;
  __syncthreads();

  // single sweep: capture every key with top-11 bits >= b1
  const unsigned int kmin = b1 << 21;
  for (int r = t; r < R_NODES; r += 1024) {
    unsigned int k2 = keys[r];
    if (k2 >= kmin) {
      unsigned int p = atomicAdd(&sh_cnt, 1u);
      if (p < 2048u)
        cand[p] = ((unsigned long long)k2 << 32) |
                  (unsigned long long)(0xFFFFFFFFu - (unsigned int)r);
    }
  }
  __syncthreads();
  const unsigned int cnt = sh_cnt > 2048u ? 2048u : sh_cnt;
  const int nsort = (cnt <= 1024u) ? 1024 : 2048;
  for (int p = t; p < nsort; p += 1024)
    if ((unsigned int)p >= cnt) cand[p] = 0ULL;
  __syncthreads();

  // bitonic ascending sort of nsort composites (key, ~idx)
  for (int ks = 2; ks <= nsort; ks <<= 1) {
    for (int js = ks >> 1; js > 0; js >>= 1) {
      for (int i = t; i < nsort; i += 1024) {
        int ixj = i ^ js;
        if (ixj > i) {
          unsigned long long x = cand[i], y = cand[ixj];
          bool up = ((i & ks) == 0);
          if (up ? (x > y) : (x < y)) {
            cand[i] = y;
            cand[ixj] = x;
          }
        }
      }
      __syncthreads();
    }
  }

  // top 512 = largest composites from the tail (desc key, asc idx on ties)
  for (int j = t; j < K_SEL; j += 1024) {
    unsigned long long c = cand[nsort - 1 - j];
    unsigned int key = (unsigned int)(c >> 32);
    unsigned int ridx = 0xFFFFFFFFu - (unsigned int)(c & 0xFFFFFFFFull);
    unsigned int ub = (key & 0x80000000u) ? (key ^ 0x80000000u) : ~key;
    float val = __uint_as_float(ub);
    sel_idx[j] = (int)ridx;
    sel_w[j] = tanhf(val);
  }
}

// ---- kernel 4: bXt[j][k] = inputs[idx_j][k] * w_j  (bf16, direct coalesced) ----
__global__ __launch_bounds__(256) void k_build_xt(const float* __restrict__ inputs,
                                                  const int* __restrict__ sel_idx,
                                                  const float* __restrict__ sel_w,
                                                  unsigned short* __restrict__ bXt) {
  const int j = blockIdx.x;
  const int c = threadIdx.x;
  const int row = sel_idx[j];
  const float w = sel_w[j];
  float2 v = *(const float2*)&inputs[(size_t)row * I_DIM + c * 2];
  ushort2 o;
  o.x = bfr(v.x * w);
  o.y = bfr(v.y * w);
  *(ushort2*)&bXt[(size_t)j * I_DIM + c * 2] = o;
}

// ---- MFMA GEMM core (UNCHANGED): D(64x64) = A1@B1 + A2@B2, bf16 in, f32 acc ----
__device__ __forceinline__ void gemm64_dual(
    const unsigned short* __restrict__ A1, const unsigned short* __restrict__ A2,
    const unsigned short* __restrict__ B1t, const unsigned short* __restrict__ B2t,
    int i0, int j0, char* smem, f32x4 acc[2][2]) {
  const int t = threadIdx.x;
  const int w = t >> 6, l = t & 63;
  const int wm = w >> 1, wn = w & 1;
  const int lr = l & 15, lh = l >> 4;
  char* sA1 = smem;
  char* sA2 = smem + 4096;
  char* sB1 = smem + 8192;
  char* sB2 = smem + 12288;
  const int srow = t >> 2;
  const int kc = t & 3;
  const int sbyte = LDS_SWZ(srow, kc * 16);

  for (int ks = 0; ks < I_DIM / 32; ++ks) {
    const size_t ga = (size_t)(i0 + srow) * I_DIM + ks * 32 + kc * 8;
    const size_t gb = (size_t)(j0 + srow) * I_DIM + ks * 32 + kc * 8;
    uint4 va1 = *(const uint4*)(A1 + ga);
    uint4 va2 = *(const uint4*)(A2 + ga);
    uint4 vb1 = *(const uint4*)(B1t + gb);
    uint4 vb2 = *(const uint4*)(B2t + gb);
    __syncthreads();
    *(uint4*)(sA1 + sbyte) = va1;
    *(uint4*)(sA2 + sbyte) = va2;
    *(uint4*)(sB1 + sbyte) = vb1;
    *(uint4*)(sB2 + sbyte) = vb2;
    __syncthreads();
    bf16x8 a1[2], a2[2], b1[2], b2[2];
#pragma unroll
    for (int mf = 0; mf < 2; ++mf) {
      int rowA = wm * 32 + mf * 16 + lr;
      int off = LDS_SWZ(rowA, lh * 16);
      a1[mf] = *(const bf16x8*)(sA1 + off);
      a2[mf] = *(const bf16x8*)(sA2 + off);
    }
#pragma unroll
    for (int nf = 0; nf < 2; ++nf) {
      int rowB = wn * 32 + nf * 16 + lr;
      int off = LDS_SWZ(rowB, lh * 16);
      b1[nf] = *(const bf16x8*)(sB1 + off);
      b2[nf] = *(const bf16x8*)(sB2 + off);
    }
#pragma unroll
    for (int mf = 0; mf < 2; ++mf)
#pragma unroll
      for (int nf = 0; nf < 2; ++nf) {
        acc[mf][nf] = __builtin_amdgcn_mfma_f32_16x16x32_bf16(a1[mf], b1[nf], acc[mf][nf], 0, 0, 0);
        acc[mf][nf] = __builtin_amdgcn_mfma_f32_16x16x32_bf16(a2[mf], b2[nf], acc[mf][nf], 0, 0, 0);
      }
  }
}

// ---- kernel 5: gates (UNCHANGED) ----
__global__ __launch_bounds__(256) void k_gates_mfma(
    const unsigned short* __restrict__ bW, const unsigned short* __restrict__ bXt,
    const unsigned short* __restrict__ bHt,
    const float* __restrict__ bu, const float* __restrict__ br,
    const float* __restrict__ hist,
    float* __restrict__ U, unsigned short* __restrict__ bRHt) {
  __shared__ char smem[16384];
  const int i0 = blockIdx.y * 64, j0 = blockIdx.x * 64;
  const int z = blockIdx.z;
  const unsigned short* A1 = bW + (size_t)(z ? 2 : 0) * (I_DIM * I_DIM);
  const unsigned short* A2 = bW + (size_t)(z ? 3 : 1) * (I_DIM * I_DIM);
  f32x4 acc[2][2];
#pragma unroll
  for (int mf = 0; mf < 2; ++mf)
#pragma unroll
    for (int nf = 0; nf < 2; ++nf) acc[mf][nf] = (f32x4){0.f, 0.f, 0.f, 0.f};
  gemm64_dual(A1, A2, bXt, bHt, i0, j0, smem, acc);

  const int t = threadIdx.x;
  const int w = t >> 6, l = t & 63;
  const int wm = w >> 1, wn = w & 1;
  const int lr = l & 15, lh = l >> 4;
  const float* bias = z ? br : bu;
#pragma unroll
  for (int mf = 0; mf < 2; ++mf)
#pragma unroll
    for (int nf = 0; nf < 2; ++nf)
#pragma unroll
      for (int q = 0; q < 4; ++q) {
        int row = i0 + wm * 32 + mf * 16 + lh * 4 + q;
        int col = j0 + wn * 32 + nf * 16 + lr;
        int o = row * I_DIM + col;
        float g = sigf(acc[mf][nf][q] + bias[o]);
        if (z == 0) {
          U[o] = g;
        } else {
          bRHt[(size_t)col * I_DIM + row] = bfr(g * hist[o]);
        }
      }
}

// ---- kernel 6: final (UNCHANGED) ----
__global__ __launch_bounds__(256) void k_final_mfma(
    const unsigned short* __restrict__ bW, const unsigned short* __restrict__ bXt,
    const unsigned short* __restrict__ bRHt,
    const float* __restrict__ bh, const float* __restrict__ U,
    const float* __restrict__ hist, float* __restrict__ out) {
  __shared__ char smem[16384];
  const int i0 = blockIdx.y * 64, j0 = blockIdx.x * 64;
  const unsigned short* A1 = bW + (size_t)4 * (I_DIM * I_DIM);
  const unsigned short* A2 = bW + (size_t)5 * (I_DIM * I_DIM);
  f32x4 acc[2][2];
#pragma unroll
  for (int mf = 0; mf < 2; ++mf)
#pragma unroll
    for (int nf = 0; nf < 2; ++nf) acc[mf][nf] = (f32x4){0.f, 0.f, 0.f, 0.f};
  gemm64_dual(A1, A2, bXt, bRHt, i0, j0, smem, acc);

  const int t = threadIdx.x;
  const int w = t >> 6, l = t & 63;
  const int wm = w >> 1, wn = w & 1;
  const int lr = l & 15, lh = l >> 4;
#pragma unroll
  for (int mf = 0; mf < 2; ++mf)
#pragma unroll
    for (int nf = 0; nf < 2; ++nf)
#pragma unroll
      for (int q = 0; q < 4; ++q) {
        int row = i0 + wm * 32 + mf * 16 + lh * 4 + q;
        int col = j0 + wn * 32 + nf * 16 + lr;
        int o = row * I_DIM + col;
        float hc = tanhf(acc[mf][nf][q] + bh[o]);
        float uu = U[o];
        out[o] = (1.f - uu) * hist[o] + uu * hc;
      }
}

extern "C" void kernel_launch(void* const* d_in, const int* in_sizes, int n_in,
                              void* d_out, int out_size, void* d_ws, size_t ws_size,
                              hipStream_t stream) {
  const float* inputs = (const float*)d_in[0];
  const float* hist   = (const float*)d_in[1];
  const float* mask   = (const float*)d_in[2];
  const float* scorer = (const float*)d_in[3];
  const float* Wu = (const float*)d_in[4];
  const float* Uu = (const float*)d_in[5];
  const float* bu = (const float*)d_in[6];
  const float* Wr = (const float*)d_in[7];
  const float* Ur = (const float*)d_in[8];
  const float* br = (const float*)d_in[9];
  const float* Wh = (const float*)d_in[10];
  const float* Uh = (const float*)d_in[11];
  const float* bh = (const float*)d_in[12];
  float* out = (float*)d_out;

  char* ws = (char*)d_ws;
  float* inv_norm = (float*)(ws + OFF_NORM);
  unsigned int* ghist = (unsigned int*)(ws + OFF_GHIST);
  unsigned int* keys = (unsigned int*)(ws + OFF_KEYS);
  int* sel_idx = (int*)(ws + OFF_SELIDX);
  float* sel_w = (float*)(ws + OFF_SELW);
  unsigned short* bXt = (unsigned short*)(ws + OFF_XT);
  unsigned short* bHt = (unsigned short*)(ws + OFF_HT);
  unsigned short* bW  = (unsigned short*)(ws + OFF_W6);
  float* U = (float*)(ws + OFF_U);
  unsigned short* bRHt = (unsigned short*)(ws + OFF_RHT);

  k_norm<<<1, 256, 0, stream>>>(scorer, inv_norm, ghist);
  k_front<<<NB_SCORES + NB_W + NB_HT, 256, 0, stream>>>(
      inputs, scorer, mask, inv_norm, keys, Wu, Uu, Wr, Ur, Wh, Uh, hist, bW, bHt);
  k_hist1<<<64, 256, 0, stream>>>(keys, ghist);
  k_select<<<1, 1024, 0, stream>>>(keys, ghist, sel_idx, sel_w);
  k_build_xt<<<512, 256, 0, stream>>>(inputs, sel_idx, sel_w, bXt);
  k_gates_mfma<<<dim3(8, 8, 2), 256, 0, stream>>>(bW, bXt, bHt, bu, br, hist, U, bRHt);
  k_final_mfma<<<dim3(8, 8), 256, 0, stream>>>(bW, bXt, bRHt, bh, U, hist, out);
}